// Round 12
// baseline (113.908 us; speedup 1.0000x reference)
//
#include <hip/hip_runtime.h>
#include <hip/hip_bf16.h>

// GCN layer: out = spmm(adj, x @ W) + bias
// Inputs: x[50000,128] f32, weight[128,128] f32, bias[128] f32,
//         edge_vals[625000] f32, edge_rows[625000] i32, edge_cols[625000] i32
// Output: out[50000,128] f32
//
// Round 12 pipeline (memset + 4 dispatches):
//   memset : lenC[98] = 0
//   K1     : blocks [0,153) coarse-bin edges into 98 slabs of 512 rows
//            (42-rec segments, ~1.2x write amp); blocks [153,217) wconv
//   split  : one block per coarse slab; LDS counting sort into 64 fine
//            buckets (8 rows); fully contiguous flush + exact lengths
//   gemm   : support = bf16(x @ W) via MFMA, single pass over x
//   bspmm  : wave per 8-row fine bucket (6250 waves = 76% wave-slot fill,
//            2x round 11); register acc, 8 gathers in flight.
// Lessons kept: float atomics on __shared__ lower to the flat path (r7/8);
// fine-grained direct binning = random 8-B scatter (r5, r10-hidden).

#define F_DIM 128

#define NBC 98                  // coarse buckets: row >> 9
#define SLABC 7360              // records per coarse slab (mean 6378, +12s)
#define NFINE 6250              // fine buckets: row >> 3 (8 rows)
#define NFINE_ALL (NBC * 64)    // 6272 (incl. padding tail)
#define SLAB_F8 160             // records per fine bucket (mean 100, +6s)

#define BIN_T 256
#define BIN_EPT 16
#define BIN_CHUNK (BIN_T * BIN_EPT)     // 4096 edges per block

#define SPLIT_T 512
#define SPLIT_EPT 15            // 512*15 = 7680 >= SLABC

typedef short bf16x8 __attribute__((ext_vector_type(8)));
typedef float f32x4 __attribute__((ext_vector_type(4)));

__device__ __forceinline__ unsigned short f2bf(float f) {
    unsigned int u = __float_as_uint(f);
    u += 0x7FFFu + ((u >> 16) & 1u);   // round-to-nearest-even
    return (unsigned short)(u >> 16);
}

// ---- K1: coarse bin (blocks < nbin) + wconv (last 64 blocks) -------------
__global__ void __launch_bounds__(BIN_T)
k1_kernel(const int* __restrict__ rows, const int* __restrict__ cols,
          const float* __restrict__ vals, int* __restrict__ lenC,
          uint2* __restrict__ ebinC, int n_edges,
          const float* __restrict__ w, unsigned short* __restrict__ wt,
          int nbin) {
    __shared__ int lcnt[NBC];
    __shared__ int lbase[NBC];
    __shared__ int garr[NBC];
    __shared__ int partial[128];
    __shared__ uint2 srec[BIN_CHUNK];      // 32 KB
    __shared__ unsigned char sbkt[BIN_CHUNK];

    const int t = threadIdx.x;

    if ((int)blockIdx.x >= nbin) {
        // wt[n][k] = bf16(w[k][n])
        int idx = (blockIdx.x - nbin) * BIN_T + t;
        int n = idx >> 7, k = idx & 127;
        wt[n * F_DIM + k] = f2bf(w[k * F_DIM + n]);
        return;
    }

    const int base = blockIdx.x * BIN_CHUNK;

    for (int i = t; i < NBC; i += BIN_T) lcnt[i] = 0;
    __syncthreads();

    unsigned int mykey[BIN_EPT];
    float myval[BIN_EPT];
    bool myok[BIN_EPT];
#pragma unroll
    for (int j = 0; j < BIN_EPT; j++) {
        int e = base + j * BIN_T + t;
        myok[j] = (e < n_edges);
        if (myok[j]) {
            int r = rows[e];
            int c = cols[e];
            myval[j] = vals[e];
            mykey[j] = ((unsigned)r << 16) | (unsigned)c;
            atomicAdd(&lcnt[r >> 9], 1);
        }
    }
    __syncthreads();

    // exclusive scan of lcnt[0..NBC) via Hillis-Steele over 128 slots
    if (t < 128) partial[t] = (t < NBC) ? lcnt[t] : 0;
    __syncthreads();
    for (int d = 1; d < 128; d <<= 1) {
        int u = (t < 128 && t >= d) ? partial[t - d] : 0;
        __syncthreads();
        if (t < 128) partial[t] += u;
        __syncthreads();
    }
    if (t < NBC) {
        lbase[t] = partial[t] - lcnt[t];
        if (lcnt[t] > 0)
            garr[t] = t * SLABC + atomicAdd(&lenC[t], lcnt[t]);
    }
    __syncthreads();
    if (t < NBC) lcnt[t] = lbase[t];   // running placement position
    __syncthreads();

#pragma unroll
    for (int j = 0; j < BIN_EPT; j++) {
        if (myok[j]) {
            int b = (int)(mykey[j] >> 25);        // row >> 9
            int p = atomicAdd(&lcnt[b], 1);
            srec[p] = make_uint2(mykey[j], __float_as_uint(myval[j]));
            sbkt[p] = (unsigned char)b;
        }
    }
    __syncthreads();

    const int m = min(BIN_CHUNK, n_edges - base);
    for (int i = t; i < m; i += BIN_T) {
        int b = sbkt[i];
        int dst = garr[b] + (i - lbase[b]);
        if (dst < (b + 1) * SLABC) ebinC[dst] = srec[i];  // overflow guard
    }
}

// ---- split: one block per coarse slab -> 64 fine 8-row buckets -----------
__global__ void __launch_bounds__(SPLIT_T)
split_kernel(const int* __restrict__ lenC, const uint2* __restrict__ ebinC,
             uint2* __restrict__ ebin2, int* __restrict__ flen) {
    __shared__ int cnt[64];
    __shared__ int lb[64];
    __shared__ int pos[64];
    __shared__ int sc[64];
    __shared__ uint2 srec[SLABC];     // 57.5 KB

    const int b = blockIdx.x;
    const int t = threadIdx.x;
    const int n = min(lenC[b], SLABC);
    const uint2* src = ebinC + (size_t)b * SLABC;

    if (t < 64) cnt[t] = 0;
    __syncthreads();

    uint2 myr[SPLIT_EPT];
    int myfb[SPLIT_EPT];
#pragma unroll
    for (int j = 0; j < SPLIT_EPT; j++) {
        int idx = j * SPLIT_T + t;
        myfb[j] = -1;
        if (idx < n) {
            myr[j] = src[idx];
            myfb[j] = (int)((myr[j].x >> 19) & 63u);   // (row>>3) & 63
            atomicAdd(&cnt[myfb[j]], 1);
        }
    }
    __syncthreads();

    // exclusive scan of the 64 counts
    if (t < 64) sc[t] = cnt[t];
    __syncthreads();
    for (int d = 1; d < 64; d <<= 1) {
        int u = (t < 64 && t >= d) ? sc[t - d] : 0;
        __syncthreads();
        if (t < 64) sc[t] += u;
        __syncthreads();
    }
    if (t < 64) {
        lb[t] = sc[t] - cnt[t];
        pos[t] = lb[t];
    }
    __syncthreads();

    // place into sorted LDS buffer
#pragma unroll
    for (int j = 0; j < SPLIT_EPT; j++) {
        if (myfb[j] >= 0) {
            int p = atomicAdd(&pos[myfb[j]], 1);
            srec[p] = myr[j];
        }
    }
    __syncthreads();

    // contiguous flush per fine bucket + exact lengths
    for (int i = t; i < n; i += SPLIT_T) {
        uint2 r = srec[i];
        int fb = (int)((r.x >> 19) & 63u);
        int o = i - lb[fb];
        if (o < SLAB_F8)
            ebin2[(size_t)(b * 64 + fb) * SLAB_F8 + o] = r;
    }
    if (t < 64) flen[b * 64 + t] = min(cnt[t], SLAB_F8);
}

// ---- GEMM: support_bf16 = bf16(x @ W), single pass over x ----------------
__global__ void __launch_bounds__(256)
gemm_mfma_kernel(const float* __restrict__ x, const unsigned short* __restrict__ wt,
                 unsigned short* __restrict__ support) {
    const int tid = threadIdx.x;
    const int wid = tid >> 6;
    const int lane = tid & 63;
    const int l15 = lane & 15;
    const int lhi = lane >> 4;           // 0..3

    const int m0 = blockIdx.x * 16;      // 3125 blocks
    const int n0 = wid * 32;

    const float* xrow = x + (size_t)(m0 + l15) * F_DIM + lhi * 8;
    const unsigned short* wrow0 = wt + (size_t)(n0 + l15) * F_DIM + lhi * 8;
    const unsigned short* wrow1 = wrow0 + 16 * F_DIM;

    f32x4 acc0 = {0.f, 0.f, 0.f, 0.f};
    f32x4 acc1 = {0.f, 0.f, 0.f, 0.f};
#pragma unroll
    for (int k0 = 0; k0 < F_DIM; k0 += 32) {
        float4 xa = *reinterpret_cast<const float4*>(xrow + k0);
        float4 xb = *reinterpret_cast<const float4*>(xrow + k0 + 4);
        bf16x8 a, b0, b1;
        a[0] = (short)f2bf(xa.x); a[1] = (short)f2bf(xa.y);
        a[2] = (short)f2bf(xa.z); a[3] = (short)f2bf(xa.w);
        a[4] = (short)f2bf(xb.x); a[5] = (short)f2bf(xb.y);
        a[6] = (short)f2bf(xb.z); a[7] = (short)f2bf(xb.w);
        b0 = *reinterpret_cast<const bf16x8*>(wrow0 + k0);
        b1 = *reinterpret_cast<const bf16x8*>(wrow1 + k0);
        acc0 = __builtin_amdgcn_mfma_f32_16x16x32_bf16(a, b0, acc0, 0, 0, 0);
        acc1 = __builtin_amdgcn_mfma_f32_16x16x32_bf16(a, b1, acc1, 0, 0, 0);
    }

    unsigned short* sp = support + (size_t)(m0 + 4 * lhi) * F_DIM + n0 + l15;
#pragma unroll
    for (int i = 0; i < 4; i++) {
        sp[(size_t)i * F_DIM]      = f2bf(acc0[i]);
        sp[(size_t)i * F_DIM + 16] = f2bf(acc1[i]);
    }
}

// ---- bspmm: wave per 8-row fine bucket; register acc + uniform switch ----
#define UPD(KEY, VAL, SV)                                                     \
    {                                                                         \
        float v = __uint_as_float(VAL);                                       \
        float cx = v * __uint_as_float((SV) << 16);                           \
        float cy = v * __uint_as_float((SV) & 0xFFFF0000u);                   \
        switch (((KEY) >> 16) & 7u) { /* wave-uniform */                      \
        case 0: ax[0] += cx; ay[0] += cy; break;                              \
        case 1: ax[1] += cx; ay[1] += cy; break;                              \
        case 2: ax[2] += cx; ay[2] += cy; break;                              \
        case 3: ax[3] += cx; ay[3] += cy; break;                              \
        case 4: ax[4] += cx; ay[4] += cy; break;                              \
        case 5: ax[5] += cx; ay[5] += cy; break;                              \
        case 6: ax[6] += cx; ay[6] += cy; break;                              \
        case 7: ax[7] += cx; ay[7] += cy; break;                              \
        }                                                                     \
    }

__global__ void __launch_bounds__(64)
bspmm_kernel(const unsigned short* __restrict__ support,
             const uint2* __restrict__ ebin2, const int* __restrict__ flen,
             const float* __restrict__ bias, float* __restrict__ out) {
    const int fbg = blockIdx.x;          // one wave per 8-row bucket
    const int lane = threadIdx.x;
    const unsigned foff = lane * 2u;

    const int s = fbg * SLAB_F8;
    const int e = s + flen[fbg];

    float ax[8], ay[8];
#pragma unroll
    for (int r = 0; r < 8; r++) { ax[r] = 0.f; ay[r] = 0.f; }

#define GATHER(K) (*reinterpret_cast<const unsigned*>(                        \
        support + (size_t)((K) & 0xffffu) * F_DIM + foff))

    int i = s;
    if (i + 7 < e) {
        uint4 ra = *reinterpret_cast<const uint4*>(&ebin2[i]);
        uint4 rb = *reinterpret_cast<const uint4*>(&ebin2[i + 2]);
        uint4 rc = *reinterpret_cast<const uint4*>(&ebin2[i + 4]);
        uint4 rd = *reinterpret_cast<const uint4*>(&ebin2[i + 6]);
#pragma unroll 1
        while (true) {
            unsigned s0 = GATHER(ra.x), s1 = GATHER(ra.z);
            unsigned s2 = GATHER(rb.x), s3 = GATHER(rb.z);
            unsigned s4 = GATHER(rc.x), s5 = GATHER(rc.z);
            unsigned s6 = GATHER(rd.x), s7 = GATHER(rd.z);
            const int inext = i + 8;
            const bool more = (inext + 7 < e);
            uint4 na, nb, nc, nd;
            if (more) {
                na = *reinterpret_cast<const uint4*>(&ebin2[inext]);
                nb = *reinterpret_cast<const uint4*>(&ebin2[inext + 2]);
                nc = *reinterpret_cast<const uint4*>(&ebin2[inext + 4]);
                nd = *reinterpret_cast<const uint4*>(&ebin2[inext + 6]);
            }
            UPD(ra.x, ra.y, s0) UPD(ra.z, ra.w, s1)
            UPD(rb.x, rb.y, s2) UPD(rb.z, rb.w, s3)
            UPD(rc.x, rc.y, s4) UPD(rc.z, rc.w, s5)
            UPD(rd.x, rd.y, s6) UPD(rd.z, rd.w, s7)
            i = inext;
            if (!more) break;
            ra = na; rb = nb; rc = nc; rd = nd;
        }
    }
#pragma unroll 1
    for (; i < e; i++) {
        uint2 r = ebin2[i];
        unsigned sv = GATHER(r.x);
        UPD(r.x, r.y, sv)
    }
#undef GATHER

    // epilogue: out[fbg*8 + r] = acc[r] + bias  (rows < 50000 since fbg < 6250)
    const float2 bb = *reinterpret_cast<const float2*>(bias + foff);
    float* op = out + (size_t)fbg * 8 * F_DIM + foff;
#pragma unroll
    for (int r = 0; r < 8; r++) {
        float2 o = make_float2(ax[r] + bb.x, ay[r] + bb.y);
        *reinterpret_cast<float2*>(op + (size_t)r * F_DIM) = o;
    }
}
#undef UPD

extern "C" void kernel_launch(void* const* d_in, const int* in_sizes, int n_in,
                              void* d_out, int out_size, void* d_ws, size_t ws_size,
                              hipStream_t stream) {
    const float* x      = (const float*)d_in[0];
    const float* weight = (const float*)d_in[1];
    const float* bias   = (const float*)d_in[2];
    const float* evals  = (const float*)d_in[3];
    const int*   erows  = (const int*)d_in[4];
    const int*   ecols  = (const int*)d_in[5];
    float* out = (float*)d_out;

    const int n_nodes = in_sizes[0] / F_DIM;   // 50000
    const int n_edges = in_sizes[3];           // 625000

    // Workspace layout (~26.7 MB)
    unsigned short* support = (unsigned short*)d_ws;                  // 12.8 MB
    unsigned short* wt      = support + (size_t)n_nodes * F_DIM;      // 32 KB
    int* lenC = (int*)(wt + F_DIM * F_DIM);                           // NBC
    int* flen = lenC + 128;                                           // NFINE_ALL
    uintptr_t ep = (uintptr_t)(flen + NFINE_ALL);
    ep = (ep + 15) & ~(uintptr_t)15;
    uint2* ebinC = (uint2*)ep;                                        // 5.77 MB
    uint2* ebin2 = ebinC + (size_t)NBC * SLABC;                       // 8.03 MB

    // 0) zero the coarse slab lengths
    hipMemsetAsync(lenC, 0, NBC * sizeof(int), stream);

    // 1) coarse bin (153 blocks) + wconv (64 blocks)
    int nbin = (n_edges + BIN_CHUNK - 1) / BIN_CHUNK;                 // 153
    k1_kernel<<<nbin + 64, BIN_T, 0, stream>>>(erows, ecols, evals, lenC,
                                               ebinC, n_edges, weight, wt, nbin);

    // 2) split each coarse slab into 64 fine 8-row buckets (contiguous)
    split_kernel<<<NBC, SPLIT_T, 0, stream>>>(lenC, ebinC, ebin2, flen);

    // 3) support = bf16(x @ W) via MFMA (single pass over x)
    gemm_mfma_kernel<<<n_nodes / 16, 256, 0, stream>>>(x, wt, support);

    // 4) wave-per-fine-bucket pull-spmm: register acc, 6250 waves
    bspmm_kernel<<<NFINE, 64, 0, stream>>>(support, ebin2, flen, bias, out);
}

// Round 13
// 93.977 us; speedup vs baseline: 1.2121x; 1.2121x over previous
//
#include <hip/hip_runtime.h>
#include <hip/hip_bf16.h>

// GCN layer: out = spmm(adj, x @ W) + bias
// Inputs: x[50000,128] f32, weight[128,128] f32, bias[128] f32,
//         edge_vals[625000] f32, edge_rows[625000] i32, edge_cols[625000] i32
// Output: out[50000,128] f32
//
// Round 13 pipeline (memset + 4 dispatches):
//   memset : lenC[98] = 0
//   K1     : blocks [0,153) coarse-bin edges into 98 slabs of 512 rows;
//            blocks [153,217) wconv (wt = bf16(w^T))
//   split  : one block per coarse slab; LDS counting sort by FULL ROW
//            (512 counters) -> row-sorted contiguous records + CSR
//            roff/rlen per row
//   gemm   : support = bf16(x @ W) via MFMA, single pass over x
//   bspmm  : wave per row; single accumulator pair, NO per-record row
//            dispatch (r12 lesson: the row switch if-converts to ~50
//            VALU/record -> VALU-bound at 61us; CSR removes it).
// Lessons kept: float atomics on __shared__ lower to the flat path (r7/8);
// fine-grained direct global binning = random 8-B scatter (r5).

#define F_DIM 128

#define NBC 98                  // coarse buckets: row >> 9
#define SLABC 7360              // records per coarse slab (mean 6378, +12s)
#define NROW_PAD (NBC * 512)    // 50176

#define BIN_T 256
#define BIN_EPT 16
#define BIN_CHUNK (BIN_T * BIN_EPT)     // 4096 edges per block

#define SPLIT_T 512
#define SPLIT_EPT 15            // 512*15 = 7680 >= SLABC

typedef short bf16x8 __attribute__((ext_vector_type(8)));
typedef float f32x4 __attribute__((ext_vector_type(4)));

__device__ __forceinline__ unsigned short f2bf(float f) {
    unsigned int u = __float_as_uint(f);
    u += 0x7FFFu + ((u >> 16) & 1u);   // round-to-nearest-even
    return (unsigned short)(u >> 16);
}

// ---- K1: coarse bin (blocks < nbin) + wconv (last 64 blocks) -------------
__global__ void __launch_bounds__(BIN_T)
k1_kernel(const int* __restrict__ rows, const int* __restrict__ cols,
          const float* __restrict__ vals, int* __restrict__ lenC,
          uint2* __restrict__ ebinC, int n_edges,
          const float* __restrict__ w, unsigned short* __restrict__ wt,
          int nbin) {
    __shared__ int lcnt[NBC];
    __shared__ int lbase[NBC];
    __shared__ int garr[NBC];
    __shared__ int partial[128];
    __shared__ uint2 srec[BIN_CHUNK];      // 32 KB
    __shared__ unsigned char sbkt[BIN_CHUNK];

    const int t = threadIdx.x;

    if ((int)blockIdx.x >= nbin) {
        // wt[n][k] = bf16(w[k][n])
        int idx = (blockIdx.x - nbin) * BIN_T + t;
        int n = idx >> 7, k = idx & 127;
        wt[n * F_DIM + k] = f2bf(w[k * F_DIM + n]);
        return;
    }

    const int base = blockIdx.x * BIN_CHUNK;

    for (int i = t; i < NBC; i += BIN_T) lcnt[i] = 0;
    __syncthreads();

    unsigned int mykey[BIN_EPT];
    float myval[BIN_EPT];
    bool myok[BIN_EPT];
#pragma unroll
    for (int j = 0; j < BIN_EPT; j++) {
        int e = base + j * BIN_T + t;
        myok[j] = (e < n_edges);
        if (myok[j]) {
            int r = rows[e];
            int c = cols[e];
            myval[j] = vals[e];
            mykey[j] = ((unsigned)r << 16) | (unsigned)c;
            atomicAdd(&lcnt[r >> 9], 1);
        }
    }
    __syncthreads();

    // exclusive scan of lcnt[0..NBC) via Hillis-Steele over 128 slots
    if (t < 128) partial[t] = (t < NBC) ? lcnt[t] : 0;
    __syncthreads();
    for (int d = 1; d < 128; d <<= 1) {
        int u = (t < 128 && t >= d) ? partial[t - d] : 0;
        __syncthreads();
        if (t < 128) partial[t] += u;
        __syncthreads();
    }
    if (t < NBC) {
        lbase[t] = partial[t] - lcnt[t];
        if (lcnt[t] > 0)
            garr[t] = t * SLABC + atomicAdd(&lenC[t], lcnt[t]);
    }
    __syncthreads();
    if (t < NBC) lcnt[t] = lbase[t];   // running placement position
    __syncthreads();

#pragma unroll
    for (int j = 0; j < BIN_EPT; j++) {
        if (myok[j]) {
            int b = (int)(mykey[j] >> 25);        // row >> 9
            int p = atomicAdd(&lcnt[b], 1);
            srec[p] = make_uint2(mykey[j], __float_as_uint(myval[j]));
            sbkt[p] = (unsigned char)b;
        }
    }
    __syncthreads();

    const int m = min(BIN_CHUNK, n_edges - base);
    for (int i = t; i < m; i += BIN_T) {
        int b = sbkt[i];
        int dst = garr[b] + (i - lbase[b]);
        if (dst < (b + 1) * SLABC) ebinC[dst] = srec[i];  // overflow guard
    }
}

// ---- split: one block per coarse slab -> row-sorted records + CSR --------
__global__ void __launch_bounds__(SPLIT_T)
split_kernel(const int* __restrict__ lenC, const uint2* __restrict__ ebinC,
             uint2* __restrict__ ebin2, int* __restrict__ roff,
             int* __restrict__ rlen) {
    __shared__ int cnt[SPLIT_T];     // per-row counts (512 rows)
    __shared__ int lb[SPLIT_T];      // exclusive prefix
    __shared__ int pos[SPLIT_T];     // scan buffer, then running placement
    __shared__ uint2 srec[SLABC];    // 57.5 KB

    const int b = blockIdx.x;
    const int t = threadIdx.x;
    const int n = min(lenC[b], SLABC);
    const uint2* src = ebinC + (size_t)b * SLABC;

    cnt[t] = 0;
    __syncthreads();

    uint2 myr[SPLIT_EPT];
    int myrow[SPLIT_EPT];
#pragma unroll
    for (int j = 0; j < SPLIT_EPT; j++) {
        int idx = j * SPLIT_T + t;
        myrow[j] = -1;
        if (idx < n) {
            myr[j] = src[idx];
            myrow[j] = (int)((myr[j].x >> 16) & 511u);   // row within slab
            atomicAdd(&cnt[myrow[j]], 1);
        }
    }
    __syncthreads();

    // exclusive scan over the 512 counters (Hillis-Steele)
    int myc = cnt[t];
    pos[t] = myc;
    __syncthreads();
    for (int d = 1; d < SPLIT_T; d <<= 1) {
        int u = (t >= d) ? pos[t - d] : 0;
        __syncthreads();
        pos[t] += u;
        __syncthreads();
    }
    lb[t] = pos[t] - myc;
    __syncthreads();
    pos[t] = lb[t];
    __syncthreads();

    // place into row-sorted LDS buffer
#pragma unroll
    for (int j = 0; j < SPLIT_EPT; j++) {
        if (myrow[j] >= 0) {
            int p = atomicAdd(&pos[myrow[j]], 1);
            srec[p] = myr[j];
        }
    }
    __syncthreads();

    // fully coalesced flush + CSR
    const int gbase = b * SLABC;
    for (int i = t; i < n; i += SPLIT_T)
        ebin2[gbase + i] = srec[i];
    roff[(b << 9) + t] = gbase + lb[t];
    rlen[(b << 9) + t] = myc;
}

// ---- GEMM: support_bf16 = bf16(x @ W), single pass over x ----------------
__global__ void __launch_bounds__(256)
gemm_mfma_kernel(const float* __restrict__ x, const unsigned short* __restrict__ wt,
                 unsigned short* __restrict__ support) {
    const int tid = threadIdx.x;
    const int wid = tid >> 6;
    const int lane = tid & 63;
    const int l15 = lane & 15;
    const int lhi = lane >> 4;           // 0..3

    const int m0 = blockIdx.x * 16;      // 3125 blocks
    const int n0 = wid * 32;

    const float* xrow = x + (size_t)(m0 + l15) * F_DIM + lhi * 8;
    const unsigned short* wrow0 = wt + (size_t)(n0 + l15) * F_DIM + lhi * 8;
    const unsigned short* wrow1 = wrow0 + 16 * F_DIM;

    f32x4 acc0 = {0.f, 0.f, 0.f, 0.f};
    f32x4 acc1 = {0.f, 0.f, 0.f, 0.f};
#pragma unroll
    for (int k0 = 0; k0 < F_DIM; k0 += 32) {
        float4 xa = *reinterpret_cast<const float4*>(xrow + k0);
        float4 xb = *reinterpret_cast<const float4*>(xrow + k0 + 4);
        bf16x8 a, b0, b1;
        a[0] = (short)f2bf(xa.x); a[1] = (short)f2bf(xa.y);
        a[2] = (short)f2bf(xa.z); a[3] = (short)f2bf(xa.w);
        a[4] = (short)f2bf(xb.x); a[5] = (short)f2bf(xb.y);
        a[6] = (short)f2bf(xb.z); a[7] = (short)f2bf(xb.w);
        b0 = *reinterpret_cast<const bf16x8*>(wrow0 + k0);
        b1 = *reinterpret_cast<const bf16x8*>(wrow1 + k0);
        acc0 = __builtin_amdgcn_mfma_f32_16x16x32_bf16(a, b0, acc0, 0, 0, 0);
        acc1 = __builtin_amdgcn_mfma_f32_16x16x32_bf16(a, b1, acc1, 0, 0, 0);
    }

    unsigned short* sp = support + (size_t)(m0 + 4 * lhi) * F_DIM + n0 + l15;
#pragma unroll
    for (int i = 0; i < 4; i++) {
        sp[(size_t)i * F_DIM]      = f2bf(acc0[i]);
        sp[(size_t)i * F_DIM + 16] = f2bf(acc1[i]);
    }
}

// ---- bspmm: wave per row; contiguous CSR records, single acc pair --------
__global__ void __launch_bounds__(256)
bspmm_kernel(const unsigned short* __restrict__ support,
             const uint2* __restrict__ ebin2, const int* __restrict__ roff,
             const int* __restrict__ rlen, const float* __restrict__ bias,
             float* __restrict__ out, int n_nodes) {
    const int row = blockIdx.x * 4 + (threadIdx.x >> 6);
    const int lane = threadIdx.x & 63;
    const unsigned foff = lane * 2u;
    if (row >= n_nodes) return;

    const int s = roff[row];
    const int n = rlen[row];

    float accx = 0.f, accy = 0.f;

#define GATHER(K) (*reinterpret_cast<const unsigned*>(                        \
        support + (size_t)((K) & 0xffffu) * F_DIM + foff))
#define ACC(KEY, VAL, SV)                                                     \
    {                                                                         \
        float v = __uint_as_float(VAL);                                       \
        accx += v * __uint_as_float((SV) << 16);                              \
        accy += v * __uint_as_float((SV) & 0xFFFF0000u);                      \
    }

    int i = 0;
#pragma unroll 1
    for (; i + 3 < n; i += 4) {        // 4 records: 4 uniform loads, 4 gathers
        uint2 r0 = ebin2[s + i];
        uint2 r1 = ebin2[s + i + 1];
        uint2 r2 = ebin2[s + i + 2];
        uint2 r3 = ebin2[s + i + 3];
        unsigned s0 = GATHER(r0.x);
        unsigned s1 = GATHER(r1.x);
        unsigned s2 = GATHER(r2.x);
        unsigned s3 = GATHER(r3.x);
        ACC(r0.x, r0.y, s0)
        ACC(r1.x, r1.y, s1)
        ACC(r2.x, r2.y, s2)
        ACC(r3.x, r3.y, s3)
    }
#pragma unroll 1
    for (; i < n; i++) {
        uint2 r = ebin2[s + i];
        unsigned sv = GATHER(r.x);
        ACC(r.x, r.y, sv)
    }
#undef GATHER
#undef ACC

    const float2 bb = *reinterpret_cast<const float2*>(bias + foff);
    float2 o = make_float2(accx + bb.x, accy + bb.y);
    *reinterpret_cast<float2*>(out + (size_t)row * F_DIM + foff) = o;
}

extern "C" void kernel_launch(void* const* d_in, const int* in_sizes, int n_in,
                              void* d_out, int out_size, void* d_ws, size_t ws_size,
                              hipStream_t stream) {
    const float* x      = (const float*)d_in[0];
    const float* weight = (const float*)d_in[1];
    const float* bias   = (const float*)d_in[2];
    const float* evals  = (const float*)d_in[3];
    const int*   erows  = (const int*)d_in[4];
    const int*   ecols  = (const int*)d_in[5];
    float* out = (float*)d_out;

    const int n_nodes = in_sizes[0] / F_DIM;   // 50000
    const int n_edges = in_sizes[3];           // 625000

    // Workspace layout (~25 MB)
    unsigned short* support = (unsigned short*)d_ws;                  // 12.8 MB
    unsigned short* wt      = support + (size_t)n_nodes * F_DIM;      // 32 KB
    int* lenC = (int*)(wt + F_DIM * F_DIM);                           // 128
    int* roff = lenC + 128;                                           // 50176
    int* rlen = roff + NROW_PAD;                                      // 50176
    uintptr_t ep = (uintptr_t)(rlen + NROW_PAD);
    ep = (ep + 15) & ~(uintptr_t)15;
    uint2* ebinC = (uint2*)ep;                                        // 5.77 MB
    uint2* ebin2 = ebinC + (size_t)NBC * SLABC;                       // 5.77 MB

    // 0) zero the coarse slab lengths
    hipMemsetAsync(lenC, 0, NBC * sizeof(int), stream);

    // 1) coarse bin (153 blocks) + wconv (64 blocks)
    int nbin = (n_edges + BIN_CHUNK - 1) / BIN_CHUNK;                 // 153
    k1_kernel<<<nbin + 64, BIN_T, 0, stream>>>(erows, ecols, evals, lenC,
                                               ebinC, n_edges, weight, wt, nbin);

    // 2) split each coarse slab into row-sorted records + CSR
    split_kernel<<<NBC, SPLIT_T, 0, stream>>>(lenC, ebinC, ebin2, roff, rlen);

    // 3) support = bf16(x @ W) via MFMA (single pass over x)
    gemm_mfma_kernel<<<n_nodes / 16, 256, 0, stream>>>(x, wt, support);

    // 4) wave-per-row pull-spmm over CSR: no switch, no atomics
    bspmm_kernel<<<(n_nodes + 3) / 4, 256, 0, stream>>>(support, ebin2, roff,
                                                        rlen, bias, out, n_nodes);
}

// Round 14
// 90.028 us; speedup vs baseline: 1.2652x; 1.0439x over previous
//
#include <hip/hip_runtime.h>
#include <hip/hip_bf16.h>

// GCN layer: out = spmm(adj, x @ W) + bias
// Inputs: x[50000,128] f32, weight[128,128] f32, bias[128] f32,
//         edge_vals[625000] f32, edge_rows[625000] i32, edge_cols[625000] i32
// Output: out[50000,128] f32
//
// Round 14 pipeline (memset + 4 dispatches):
//   memset : lenC[98] = 0
//   K1     : 306 blocks coarse-bin 2048 edges each into 98 slabs of 512
//            rows (shfl-scan); 64 more blocks do wconv (wt = bf16(w^T))
//   split  : one block per coarse slab; LDS counting sort by full row
//            (shfl-scan, 6 barriers) -> row-sorted records + CSR roff/rlen
//   gemm   : support = bf16(x @ W) via MFMA, single pass over x
//   bspmm  : wave per row; dual-half lanes (even/odd records), 8 records
//            in flight, shfl_xor(32) merge.
// Lessons kept: float atomics on __shared__ lower to the flat path (r7/8);
// per-record row switch if-converts to ~50 VALU/record (r12); fine-grained
// direct global binning = random 8-B scatter (r5).

#define F_DIM 128

#define NBC 98                  // coarse buckets: row >> 9
#define SLABC 7360              // records per coarse slab (mean 6378, +12s)
#define NROW_PAD (NBC * 512)    // 50176

#define BIN_T 256
#define BIN_EPT 8
#define BIN_CHUNK (BIN_T * BIN_EPT)     // 2048 edges per block

#define SPLIT_T 512
#define SPLIT_EPT 15            // 512*15 = 7680 >= SLABC

typedef short bf16x8 __attribute__((ext_vector_type(8)));
typedef float f32x4 __attribute__((ext_vector_type(4)));

__device__ __forceinline__ unsigned short f2bf(float f) {
    unsigned int u = __float_as_uint(f);
    u += 0x7FFFu + ((u >> 16) & 1u);   // round-to-nearest-even
    return (unsigned short)(u >> 16);
}

// ---- K1: coarse bin (blocks < nbin) + wconv (last 64 blocks) -------------
__global__ void __launch_bounds__(BIN_T)
k1_kernel(const int* __restrict__ rows, const int* __restrict__ cols,
          const float* __restrict__ vals, int* __restrict__ lenC,
          uint2* __restrict__ ebinC, int n_edges,
          const float* __restrict__ w, unsigned short* __restrict__ wt,
          int nbin) {
    __shared__ int lcnt[NBC];     // counts -> running placement pos
    __shared__ int lbase[NBC];    // local exclusive prefix
    __shared__ int garr[NBC];     // reserved global base
    __shared__ int w0sum;
    __shared__ uint2 srec[BIN_CHUNK];      // 16 KB
    __shared__ unsigned char sbkt[BIN_CHUNK];

    const int t = threadIdx.x;

    if ((int)blockIdx.x >= nbin) {
        // wt[n][k] = bf16(w[k][n])
        int idx = (blockIdx.x - nbin) * BIN_T + t;
        int n = idx >> 7, k = idx & 127;
        wt[n * F_DIM + k] = f2bf(w[k * F_DIM + n]);
        return;
    }

    const int base = blockIdx.x * BIN_CHUNK;

    if (t < NBC) lcnt[t] = 0;
    __syncthreads();

    unsigned int mykey[BIN_EPT];
    float myval[BIN_EPT];
    bool myok[BIN_EPT];
#pragma unroll
    for (int j = 0; j < BIN_EPT; j++) {
        int e = base + j * BIN_T + t;
        myok[j] = (e < n_edges);
        if (myok[j]) {
            int r = rows[e];
            int c = cols[e];
            myval[j] = vals[e];
            mykey[j] = ((unsigned)r << 16) | (unsigned)c;
            atomicAdd(&lcnt[r >> 9], 1);
        }
    }
    __syncthreads();

    // exclusive scan over NBC<=128 buckets: shfl within 2 waves + combine
    const int lane = t & 63;
    int cval = 0, inc = 0;
    if (t < 128) {
        cval = (t < NBC) ? lcnt[t] : 0;
        inc = cval;
#pragma unroll
        for (int d = 1; d < 64; d <<= 1) {
            int u = __shfl_up(inc, d);
            if (lane >= d) inc += u;
        }
        if (t == 63) w0sum = inc;
    }
    __syncthreads();
    if (t >= 64 && t < 128) inc += w0sum;
    if (t < NBC) {
        int lb = inc - cval;
        lbase[t] = lb;
        if (cval > 0) garr[t] = t * SLABC + atomicAdd(&lenC[t], cval);
        lcnt[t] = lb;            // running placement position
    }
    __syncthreads();

#pragma unroll
    for (int j = 0; j < BIN_EPT; j++) {
        if (myok[j]) {
            int b = (int)(mykey[j] >> 25);        // row >> 9
            int p = atomicAdd(&lcnt[b], 1);
            srec[p] = make_uint2(mykey[j], __float_as_uint(myval[j]));
            sbkt[p] = (unsigned char)b;
        }
    }
    __syncthreads();

    const int m = min(BIN_CHUNK, n_edges - base);
    for (int i = t; i < m; i += BIN_T) {
        int b = sbkt[i];
        int dst = garr[b] + (i - lbase[b]);
        if (dst < (b + 1) * SLABC) ebinC[dst] = srec[i];  // overflow guard
    }
}

// ---- split: one block per coarse slab -> row-sorted records + CSR --------
__global__ void __launch_bounds__(SPLIT_T)
split_kernel(const int* __restrict__ lenC, const uint2* __restrict__ ebinC,
             uint2* __restrict__ ebin2, int* __restrict__ roff,
             int* __restrict__ rlen) {
    __shared__ int cnt[SPLIT_T];     // per-row counts (512 rows)
    __shared__ int lb[SPLIT_T];      // exclusive prefix
    __shared__ int pos[SPLIT_T];     // running placement
    __shared__ int wsum[8], wbase[8];
    __shared__ uint2 srec[SLABC];    // 57.5 KB

    const int b = blockIdx.x;
    const int t = threadIdx.x;
    const int n = min(lenC[b], SLABC);
    const uint2* src = ebinC + (size_t)b * SLABC;

    cnt[t] = 0;
    __syncthreads();

    uint2 myr[SPLIT_EPT];
    int myrow[SPLIT_EPT];
#pragma unroll
    for (int j = 0; j < SPLIT_EPT; j++) {
        int idx = j * SPLIT_T + t;
        myrow[j] = -1;
        if (idx < n) {
            myr[j] = src[idx];
            myrow[j] = (int)((myr[j].x >> 16) & 511u);   // row within slab
            atomicAdd(&cnt[myrow[j]], 1);
        }
    }
    __syncthreads();

    // exclusive scan over 512 counters: wave shfl scans + 8-way combine
    const int lane = t & 63;
    const int wv = t >> 6;
    const int myc = cnt[t];
    int inc = myc;
#pragma unroll
    for (int d = 1; d < 64; d <<= 1) {
        int u = __shfl_up(inc, d);
        if (lane >= d) inc += u;
    }
    if (lane == 63) wsum[wv] = inc;
    __syncthreads();
    if (t == 0) {
        int run = 0;
#pragma unroll
        for (int k = 0; k < 8; k++) { wbase[k] = run; run += wsum[k]; }
    }
    __syncthreads();
    const int excl = wbase[wv] + inc - myc;
    lb[t] = excl;
    pos[t] = excl;
    __syncthreads();

    // place into row-sorted LDS buffer
#pragma unroll
    for (int j = 0; j < SPLIT_EPT; j++) {
        if (myrow[j] >= 0) {
            int p = atomicAdd(&pos[myrow[j]], 1);
            srec[p] = myr[j];
        }
    }
    __syncthreads();

    // fully coalesced flush + CSR
    const int gbase = b * SLABC;
    for (int i = t; i < n; i += SPLIT_T)
        ebin2[gbase + i] = srec[i];
    roff[(b << 9) + t] = gbase + lb[t];
    rlen[(b << 9) + t] = myc;
}

// ---- GEMM: support_bf16 = bf16(x @ W), single pass over x ----------------
__global__ void __launch_bounds__(256)
gemm_mfma_kernel(const float* __restrict__ x, const unsigned short* __restrict__ wt,
                 unsigned short* __restrict__ support) {
    const int tid = threadIdx.x;
    const int wid = tid >> 6;
    const int lane = tid & 63;
    const int l15 = lane & 15;
    const int lhi = lane >> 4;           // 0..3

    const int m0 = blockIdx.x * 16;      // 3125 blocks
    const int n0 = wid * 32;

    const float* xrow = x + (size_t)(m0 + l15) * F_DIM + lhi * 8;
    const unsigned short* wrow0 = wt + (size_t)(n0 + l15) * F_DIM + lhi * 8;
    const unsigned short* wrow1 = wrow0 + 16 * F_DIM;

    f32x4 acc0 = {0.f, 0.f, 0.f, 0.f};
    f32x4 acc1 = {0.f, 0.f, 0.f, 0.f};
#pragma unroll
    for (int k0 = 0; k0 < F_DIM; k0 += 32) {
        float4 xa = *reinterpret_cast<const float4*>(xrow + k0);
        float4 xb = *reinterpret_cast<const float4*>(xrow + k0 + 4);
        bf16x8 a, b0, b1;
        a[0] = (short)f2bf(xa.x); a[1] = (short)f2bf(xa.y);
        a[2] = (short)f2bf(xa.z); a[3] = (short)f2bf(xa.w);
        a[4] = (short)f2bf(xb.x); a[5] = (short)f2bf(xb.y);
        a[6] = (short)f2bf(xb.z); a[7] = (short)f2bf(xb.w);
        b0 = *reinterpret_cast<const bf16x8*>(wrow0 + k0);
        b1 = *reinterpret_cast<const bf16x8*>(wrow1 + k0);
        acc0 = __builtin_amdgcn_mfma_f32_16x16x32_bf16(a, b0, acc0, 0, 0, 0);
        acc1 = __builtin_amdgcn_mfma_f32_16x16x32_bf16(a, b1, acc1, 0, 0, 0);
    }

    unsigned short* sp = support + (size_t)(m0 + 4 * lhi) * F_DIM + n0 + l15;
#pragma unroll
    for (int i = 0; i < 4; i++) {
        sp[(size_t)i * F_DIM]      = f2bf(acc0[i]);
        sp[(size_t)i * F_DIM + 16] = f2bf(acc1[i]);
    }
}

// ---- bspmm: wave per row; dual-half lanes, 8 records in flight -----------
__global__ void __launch_bounds__(256)
bspmm_kernel(const unsigned short* __restrict__ support,
             const uint2* __restrict__ ebin2, const int* __restrict__ roff,
             const int* __restrict__ rlen, const float* __restrict__ bias,
             float* __restrict__ out, int n_nodes) {
    const int row = blockIdx.x * 4 + (threadIdx.x >> 6);
    const int lane = threadIdx.x & 63;
    const int half = lane >> 5;          // 0: even records, 1: odd records
    const int l32 = lane & 31;
    const unsigned coff = l32 * 4u;      // 4 bf16 columns per lane
    if (row >= n_nodes) return;

    const int s = roff[row];
    const int n = rlen[row];

    float a0 = 0.f, a1 = 0.f, a2 = 0.f, a3 = 0.f;

#define GATH(K) (*reinterpret_cast<const uint2*>(                             \
        support + (size_t)((K) & 0xffffu) * F_DIM + coff))
#define ACC4(VAL, SV)                                                         \
    {                                                                         \
        float v = __uint_as_float(VAL);                                       \
        a0 += v * __uint_as_float((SV).x << 16);                              \
        a1 += v * __uint_as_float((SV).x & 0xFFFF0000u);                      \
        a2 += v * __uint_as_float((SV).y << 16);                              \
        a3 += v * __uint_as_float((SV).y & 0xFFFF0000u);                      \
    }

    int i = 0;
#pragma unroll 1
    for (; i + 7 < n; i += 8) {          // wave handles records i..i+7
        const int j = s + i + half;      // this half: j, j+2, j+4, j+6
        uint2 r0 = ebin2[j];
        uint2 r1 = ebin2[j + 2];
        uint2 r2 = ebin2[j + 4];
        uint2 r3 = ebin2[j + 6];
        uint2 s0 = GATH(r0.x);
        uint2 s1 = GATH(r1.x);
        uint2 s2 = GATH(r2.x);
        uint2 s3 = GATH(r3.x);
        ACC4(r0.y, s0) ACC4(r1.y, s1) ACC4(r2.y, s2) ACC4(r3.y, s3)
    }
#pragma unroll 1
    for (; i + 1 < n; i += 2) {          // pairs: half0 -> i, half1 -> i+1
        uint2 r = ebin2[s + i + half];
        uint2 sv = GATH(r.x);
        ACC4(r.y, sv)
    }
    if (i < n && half == 0) {            // odd tail record
        uint2 r = ebin2[s + i];
        uint2 sv = GATH(r.x);
        ACC4(r.y, sv)
    }
#undef GATH
#undef ACC4

    // merge halves
    a0 += __shfl_xor(a0, 32);
    a1 += __shfl_xor(a1, 32);
    a2 += __shfl_xor(a2, 32);
    a3 += __shfl_xor(a3, 32);

    if (half == 0) {
        const float4 bb = *reinterpret_cast<const float4*>(bias + coff);
        float4 o = make_float4(a0 + bb.x, a1 + bb.y, a2 + bb.z, a3 + bb.w);
        *reinterpret_cast<float4*>(out + (size_t)row * F_DIM + coff) = o;
    }
}

extern "C" void kernel_launch(void* const* d_in, const int* in_sizes, int n_in,
                              void* d_out, int out_size, void* d_ws, size_t ws_size,
                              hipStream_t stream) {
    const float* x      = (const float*)d_in[0];
    const float* weight = (const float*)d_in[1];
    const float* bias   = (const float*)d_in[2];
    const float* evals  = (const float*)d_in[3];
    const int*   erows  = (const int*)d_in[4];
    const int*   ecols  = (const int*)d_in[5];
    float* out = (float*)d_out;

    const int n_nodes = in_sizes[0] / F_DIM;   // 50000
    const int n_edges = in_sizes[3];           // 625000

    // Workspace layout (~25 MB)
    unsigned short* support = (unsigned short*)d_ws;                  // 12.8 MB
    unsigned short* wt      = support + (size_t)n_nodes * F_DIM;      // 32 KB
    int* lenC = (int*)(wt + F_DIM * F_DIM);                           // 128
    int* roff = lenC + 128;                                           // 50176
    int* rlen = roff + NROW_PAD;                                      // 50176
    uintptr_t ep = (uintptr_t)(rlen + NROW_PAD);
    ep = (ep + 15) & ~(uintptr_t)15;
    uint2* ebinC = (uint2*)ep;                                        // 5.77 MB
    uint2* ebin2 = ebinC + (size_t)NBC * SLABC;                       // 5.77 MB

    // 0) zero the coarse slab lengths
    hipMemsetAsync(lenC, 0, NBC * sizeof(int), stream);

    // 1) coarse bin (306 blocks) + wconv (64 blocks)
    int nbin = (n_edges + BIN_CHUNK - 1) / BIN_CHUNK;                 // 306
    k1_kernel<<<nbin + 64, BIN_T, 0, stream>>>(erows, ecols, evals, lenC,
                                               ebinC, n_edges, weight, wt, nbin);

    // 2) split each coarse slab into row-sorted records + CSR
    split_kernel<<<NBC, SPLIT_T, 0, stream>>>(lenC, ebinC, ebin2, roff, rlen);

    // 3) support = bf16(x @ W) via MFMA (single pass over x)
    gemm_mfma_kernel<<<n_nodes / 16, 256, 0, stream>>>(x, wt, support);

    // 4) wave-per-row pull-spmm over CSR: dual-half lanes
    bspmm_kernel<<<(n_nodes + 3) / 4, 256, 0, stream>>>(support, ebin2, roff,
                                                        rlen, bias, out, n_nodes);
}

// Round 15
// 81.478 us; speedup vs baseline: 1.3980x; 1.1049x over previous
//
#include <hip/hip_runtime.h>
#include <hip/hip_bf16.h>

// GCN layer: out = spmm(adj, x @ W) + bias
// Inputs: x[50000,128] f32, weight[128,128] f32, bias[128] f32,
//         edge_vals[625000] f32, edge_rows[625000] i32, edge_cols[625000] i32
// Output: out[50000,128] f32
//
// Round 15 pipeline (4 dispatches, no memset):
//   init      : blocks 0-63 wconv (wt = bf16(w^T)); block 64 zeroes lenC
//   k1        : 306 blocks coarse-bin 2048 edges each into 98 slabs of
//               512 rows (shfl-scan, segment-flushed)
//   splitgemm : MERGED dispatch. Blocks [0,98): LDS counting sort of each
//               slab by full row -> row-sorted records + CSR. Blocks
//               [98,1661): MFMA gemm (32 rows/block, 8 waves). Split's 98
//               blocks co-schedule with gemm -> latency hidden.
//   bspmm     : wave per row over CSR; dual-half lanes, 8 records in flight.
// Lessons kept: float atomics on __shared__ lower to the flat path (r7/8);
// per-record row switch if-converts to ~50 VALU/record (r12); fine-grained
// direct global binning = random 8-B scatter (r5).

#define F_DIM 128

#define NBC 98                  // coarse buckets: row >> 9
#define SLABC 7360              // records per coarse slab (mean 6378, +12s)
#define NROW_PAD (NBC * 512)    // 50176

#define BIN_T 256
#define BIN_EPT 8
#define BIN_CHUNK (BIN_T * BIN_EPT)     // 2048 edges per block

#define SPLIT_T 512
#define SPLIT_EPT 15            // 512*15 = 7680 >= SLABC
#define GEMM_BLKS 1563          // ceil(50000/32)

typedef short bf16x8 __attribute__((ext_vector_type(8)));
typedef float f32x4 __attribute__((ext_vector_type(4)));

__device__ __forceinline__ unsigned short f2bf(float f) {
    unsigned int u = __float_as_uint(f);
    u += 0x7FFFu + ((u >> 16) & 1u);   // round-to-nearest-even
    return (unsigned short)(u >> 16);
}

// ---- init: wconv (blocks 0-63) + zero lenC (block 64) --------------------
__global__ void __launch_bounds__(256)
init_kernel(const float* __restrict__ w, unsigned short* __restrict__ wt,
            int* __restrict__ lenC) {
    if (blockIdx.x == 64) {
        if (threadIdx.x < NBC) lenC[threadIdx.x] = 0;
        return;
    }
    int idx = blockIdx.x * 256 + threadIdx.x;
    int n = idx >> 7, k = idx & 127;
    wt[n * F_DIM + k] = f2bf(w[k * F_DIM + n]);
}

// ---- k1: coarse bin into 98 slabs of 512 rows ----------------------------
__global__ void __launch_bounds__(BIN_T)
k1_kernel(const int* __restrict__ rows, const int* __restrict__ cols,
          const float* __restrict__ vals, int* __restrict__ lenC,
          uint2* __restrict__ ebinC, int n_edges) {
    __shared__ int lcnt[NBC];     // counts -> running placement pos
    __shared__ int lbase[NBC];    // local exclusive prefix
    __shared__ int garr[NBC];     // reserved global base
    __shared__ int w0sum;
    __shared__ uint2 srec[BIN_CHUNK];      // 16 KB
    __shared__ unsigned char sbkt[BIN_CHUNK];

    const int t = threadIdx.x;
    const int base = blockIdx.x * BIN_CHUNK;

    if (t < NBC) lcnt[t] = 0;
    __syncthreads();

    unsigned int mykey[BIN_EPT];
    float myval[BIN_EPT];
    bool myok[BIN_EPT];
#pragma unroll
    for (int j = 0; j < BIN_EPT; j++) {
        int e = base + j * BIN_T + t;
        myok[j] = (e < n_edges);
        if (myok[j]) {
            int r = rows[e];
            int c = cols[e];
            myval[j] = vals[e];
            mykey[j] = ((unsigned)r << 16) | (unsigned)c;
            atomicAdd(&lcnt[r >> 9], 1);
        }
    }
    __syncthreads();

    // exclusive scan over NBC<=128 buckets: shfl within 2 waves + combine
    const int lane = t & 63;
    int cval = 0, inc = 0;
    if (t < 128) {
        cval = (t < NBC) ? lcnt[t] : 0;
        inc = cval;
#pragma unroll
        for (int d = 1; d < 64; d <<= 1) {
            int u = __shfl_up(inc, d);
            if (lane >= d) inc += u;
        }
        if (t == 63) w0sum = inc;
    }
    __syncthreads();
    if (t >= 64 && t < 128) inc += w0sum;
    if (t < NBC) {
        int lb = inc - cval;
        lbase[t] = lb;
        if (cval > 0) garr[t] = t * SLABC + atomicAdd(&lenC[t], cval);
        lcnt[t] = lb;            // running placement position
    }
    __syncthreads();

#pragma unroll
    for (int j = 0; j < BIN_EPT; j++) {
        if (myok[j]) {
            int b = (int)(mykey[j] >> 25);        // row >> 9
            int p = atomicAdd(&lcnt[b], 1);
            srec[p] = make_uint2(mykey[j], __float_as_uint(myval[j]));
            sbkt[p] = (unsigned char)b;
        }
    }
    __syncthreads();

    const int m = min(BIN_CHUNK, n_edges - base);
    for (int i = t; i < m; i += BIN_T) {
        int b = sbkt[i];
        int dst = garr[b] + (i - lbase[b]);
        if (dst < (b + 1) * SLABC) ebinC[dst] = srec[i];  // overflow guard
    }
}

// ---- splitgemm: blocks [0,NBC) split; blocks [NBC, NBC+GEMM_BLKS) gemm ---
__global__ void __launch_bounds__(SPLIT_T)
splitgemm_kernel(const int* __restrict__ lenC, const uint2* __restrict__ ebinC,
                 uint2* __restrict__ ebin2, int* __restrict__ roff,
                 int* __restrict__ rlen,
                 const float* __restrict__ x, const unsigned short* __restrict__ wt,
                 unsigned short* __restrict__ support, int n_nodes) {
    __shared__ int cnt[SPLIT_T];     // per-row counts (512 rows)
    __shared__ int lb[SPLIT_T];      // exclusive prefix
    __shared__ int pos[SPLIT_T];     // running placement
    __shared__ int wsum[8], wbase[8];
    __shared__ uint2 srec[SLABC];    // 57.5 KB (total ~63.6 KB static LDS)

    const int t = threadIdx.x;

    if ((int)blockIdx.x >= NBC) {
        // ---------------- gemm path: 32 rows per block, 8 waves -----------
        const int gb = blockIdx.x - NBC;
        const int wid = t >> 6;
        const int mt = wid >> 2;             // 0/1: which 16-row m-tile
        const int nw = wid & 3;              // n-group: cols nw*32..nw*32+31
        const int lane = t & 63;
        const int l15 = lane & 15;
        const int lhi = lane >> 4;

        const int m0 = gb * 32 + mt * 16;
        const int n0 = nw * 32;

        int xr = m0 + l15;
        if (xr >= n_nodes) xr = n_nodes - 1;     // clamp OOB loads
        const float* xrow = x + (size_t)xr * F_DIM + lhi * 8;
        const unsigned short* wrow0 = wt + (size_t)(n0 + l15) * F_DIM + lhi * 8;
        const unsigned short* wrow1 = wrow0 + 16 * F_DIM;

        f32x4 acc0 = {0.f, 0.f, 0.f, 0.f};
        f32x4 acc1 = {0.f, 0.f, 0.f, 0.f};
#pragma unroll
        for (int k0 = 0; k0 < F_DIM; k0 += 32) {
            float4 xa = *reinterpret_cast<const float4*>(xrow + k0);
            float4 xb = *reinterpret_cast<const float4*>(xrow + k0 + 4);
            bf16x8 a, b0, b1;
            a[0] = (short)f2bf(xa.x); a[1] = (short)f2bf(xa.y);
            a[2] = (short)f2bf(xa.z); a[3] = (short)f2bf(xa.w);
            a[4] = (short)f2bf(xb.x); a[5] = (short)f2bf(xb.y);
            a[6] = (short)f2bf(xb.z); a[7] = (short)f2bf(xb.w);
            b0 = *reinterpret_cast<const bf16x8*>(wrow0 + k0);
            b1 = *reinterpret_cast<const bf16x8*>(wrow1 + k0);
            acc0 = __builtin_amdgcn_mfma_f32_16x16x32_bf16(a, b0, acc0, 0, 0, 0);
            acc1 = __builtin_amdgcn_mfma_f32_16x16x32_bf16(a, b1, acc1, 0, 0, 0);
        }

        // D: row = m0 + 4*lhi + i, cols n0 + l15 and n0 + 16 + l15
        unsigned short* sp = support + (size_t)(m0 + 4 * lhi) * F_DIM + n0 + l15;
#pragma unroll
        for (int i = 0; i < 4; i++) {
            int row = m0 + 4 * lhi + i;
            if (row < n_nodes) {
                sp[(size_t)i * F_DIM]      = f2bf(acc0[i]);
                sp[(size_t)i * F_DIM + 16] = f2bf(acc1[i]);
            }
        }
        return;
    }

    // ---------------- split path: row-sort one coarse slab + CSR ----------
    const int b = blockIdx.x;
    const int n = min(lenC[b], SLABC);
    const uint2* src = ebinC + (size_t)b * SLABC;

    cnt[t] = 0;
    __syncthreads();

    uint2 myr[SPLIT_EPT];
    int myrow[SPLIT_EPT];
#pragma unroll
    for (int j = 0; j < SPLIT_EPT; j++) {
        int idx = j * SPLIT_T + t;
        myrow[j] = -1;
        if (idx < n) {
            myr[j] = src[idx];
            myrow[j] = (int)((myr[j].x >> 16) & 511u);   // row within slab
            atomicAdd(&cnt[myrow[j]], 1);
        }
    }
    __syncthreads();

    // exclusive scan over 512 counters: wave shfl scans + 8-way combine
    const int lane = t & 63;
    const int wv = t >> 6;
    const int myc = cnt[t];
    int inc = myc;
#pragma unroll
    for (int d = 1; d < 64; d <<= 1) {
        int u = __shfl_up(inc, d);
        if (lane >= d) inc += u;
    }
    if (lane == 63) wsum[wv] = inc;
    __syncthreads();
    if (t == 0) {
        int run = 0;
#pragma unroll
        for (int k = 0; k < 8; k++) { wbase[k] = run; run += wsum[k]; }
    }
    __syncthreads();
    const int excl = wbase[wv] + inc - myc;
    lb[t] = excl;
    pos[t] = excl;
    __syncthreads();

    // place into row-sorted LDS buffer
#pragma unroll
    for (int j = 0; j < SPLIT_EPT; j++) {
        if (myrow[j] >= 0) {
            int p = atomicAdd(&pos[myrow[j]], 1);
            srec[p] = myr[j];
        }
    }
    __syncthreads();

    // fully coalesced flush + CSR
    const int gbase = b * SLABC;
    for (int i = t; i < n; i += SPLIT_T)
        ebin2[gbase + i] = srec[i];
    roff[(b << 9) + t] = gbase + lb[t];
    rlen[(b << 9) + t] = myc;
}

// ---- bspmm: wave per row; dual-half lanes, 8 records in flight -----------
__global__ void __launch_bounds__(256)
bspmm_kernel(const unsigned short* __restrict__ support,
             const uint2* __restrict__ ebin2, const int* __restrict__ roff,
             const int* __restrict__ rlen, const float* __restrict__ bias,
             float* __restrict__ out, int n_nodes) {
    const int row = blockIdx.x * 4 + (threadIdx.x >> 6);
    const int lane = threadIdx.x & 63;
    const int half = lane >> 5;          // 0: even records, 1: odd records
    const int l32 = lane & 31;
    const unsigned coff = l32 * 4u;      // 4 bf16 columns per lane
    if (row >= n_nodes) return;

    const int s = roff[row];
    const int n = rlen[row];

    float a0 = 0.f, a1 = 0.f, a2 = 0.f, a3 = 0.f;

#define GATH(K) (*reinterpret_cast<const uint2*>(                             \
        support + (size_t)((K) & 0xffffu) * F_DIM + coff))
#define ACC4(VAL, SV)                                                         \
    {                                                                         \
        float v = __uint_as_float(VAL);                                       \
        a0 += v * __uint_as_float((SV).x << 16);                              \
        a1 += v * __uint_as_float((SV).x & 0xFFFF0000u);                      \
        a2 += v * __uint_as_float((SV).y << 16);                              \
        a3 += v * __uint_as_float((SV).y & 0xFFFF0000u);                      \
    }

    int i = 0;
#pragma unroll 1
    for (; i + 7 < n; i += 8) {          // wave handles records i..i+7
        const int j = s + i + half;      // this half: j, j+2, j+4, j+6
        uint2 r0 = ebin2[j];
        uint2 r1 = ebin2[j + 2];
        uint2 r2 = ebin2[j + 4];
        uint2 r3 = ebin2[j + 6];
        uint2 s0 = GATH(r0.x);
        uint2 s1 = GATH(r1.x);
        uint2 s2 = GATH(r2.x);
        uint2 s3 = GATH(r3.x);
        ACC4(r0.y, s0) ACC4(r1.y, s1) ACC4(r2.y, s2) ACC4(r3.y, s3)
    }
#pragma unroll 1
    for (; i + 1 < n; i += 2) {          // pairs: half0 -> i, half1 -> i+1
        uint2 r = ebin2[s + i + half];
        uint2 sv = GATH(r.x);
        ACC4(r.y, sv)
    }
    if (i < n && half == 0) {            // odd tail record
        uint2 r = ebin2[s + i];
        uint2 sv = GATH(r.x);
        ACC4(r.y, sv)
    }
#undef GATH
#undef ACC4

    // merge halves
    a0 += __shfl_xor(a0, 32);
    a1 += __shfl_xor(a1, 32);
    a2 += __shfl_xor(a2, 32);
    a3 += __shfl_xor(a3, 32);

    if (half == 0) {
        const float4 bb = *reinterpret_cast<const float4*>(bias + coff);
        float4 o = make_float4(a0 + bb.x, a1 + bb.y, a2 + bb.z, a3 + bb.w);
        *reinterpret_cast<float4*>(out + (size_t)row * F_DIM + coff) = o;
    }
}

extern "C" void kernel_launch(void* const* d_in, const int* in_sizes, int n_in,
                              void* d_out, int out_size, void* d_ws, size_t ws_size,
                              hipStream_t stream) {
    const float* x      = (const float*)d_in[0];
    const float* weight = (const float*)d_in[1];
    const float* bias   = (const float*)d_in[2];
    const float* evals  = (const float*)d_in[3];
    const int*   erows  = (const int*)d_in[4];
    const int*   ecols  = (const int*)d_in[5];
    float* out = (float*)d_out;

    const int n_nodes = in_sizes[0] / F_DIM;   // 50000
    const int n_edges = in_sizes[3];           // 625000

    // Workspace layout (~25 MB)
    unsigned short* support = (unsigned short*)d_ws;                  // 12.8 MB
    unsigned short* wt      = support + (size_t)n_nodes * F_DIM;      // 32 KB
    int* lenC = (int*)(wt + F_DIM * F_DIM);                           // 128
    int* roff = lenC + 128;                                           // 50176
    int* rlen = roff + NROW_PAD;                                      // 50176
    uintptr_t ep = (uintptr_t)(rlen + NROW_PAD);
    ep = (ep + 15) & ~(uintptr_t)15;
    uint2* ebinC = (uint2*)ep;                                        // 5.77 MB
    uint2* ebin2 = ebinC + (size_t)NBC * SLABC;                       // 5.77 MB

    // 1) wconv + zero lenC
    init_kernel<<<65, 256, 0, stream>>>(weight, wt, lenC);

    // 2) coarse bin (306 blocks)
    int nbin = (n_edges + BIN_CHUNK - 1) / BIN_CHUNK;                 // 306
    k1_kernel<<<nbin, BIN_T, 0, stream>>>(erows, ecols, evals, lenC,
                                          ebinC, n_edges);

    // 3) merged: split (98 blocks) || gemm (1563 blocks)
    splitgemm_kernel<<<NBC + GEMM_BLKS, SPLIT_T, 0, stream>>>(
        lenC, ebinC, ebin2, roff, rlen, x, wt, support, n_nodes);

    // 4) wave-per-row pull-spmm over CSR
    bspmm_kernel<<<(n_nodes + 3) / 4, 256, 0, stream>>>(support, ebin2, roff,
                                                        rlen, bias, out, n_nodes);
}